// Round 7
// baseline (1522.430 us; speedup 1.0000x reference)
//
#include <hip/hip_runtime.h>
#include <math.h>

// PixelSnail forward, fp32. B=8, CH=1, H=W=32 (N=1024), HID=64, S=8, L=2,
// HEAD=4, QK=16 (d=4/head), VD=32 (8/head).

#define NPix 1024

__device__ __forceinline__ float elu_f(float x){ return x > 0.f ? x : __expf(x) - 1.f; }
__device__ __forceinline__ float sig_f(float x){ return 1.f / (1.f + __expf(-x)); }

// ---------------- weight transpose ----------------
// bb1 [16][64o][64i]f4 -> [16][64i][64o]f4
// bb2 [16][128o][64i]f4 -> paired [16][64i][64c][2(y,z)]f4  (y=c, z=c+64)
// qkv [8][64c][66i] -> [8][66i][64c]
__global__ __launch_bounds__(256) void k_wT(const float* __restrict__ bb1_w,
        const float* __restrict__ bb2_w, const float* __restrict__ qkv_w,
        float* __restrict__ wT1, float* __restrict__ wT2, float* __restrict__ wTq)
{
    int tid = blockIdx.x*256 + threadIdx.x;
    if (tid < 65536){
        int o = tid & 63, i = (tid>>6) & 63, sl = tid >> 12;
        reinterpret_cast<float4*>(wT1)[tid] =
            reinterpret_cast<const float4*>(bb1_w)[(sl*64 + o)*64 + i];
    }
    int t2 = tid - 65536;
    if (t2 >= 0 && t2 < 131072){
        int p = t2 & 1, c = (t2>>1) & 63, i = (t2>>7) & 63, sl = t2 >> 13;
        reinterpret_cast<float4*>(wT2)[t2] =
            reinterpret_cast<const float4*>(bb2_w)[(sl*128 + p*64 + c)*64 + i];
    }
    int t3 = tid - 196608;
    if (t3 >= 0 && t3 < 33792){
        int c = t3 & 63, rem = t3 >> 6, i = rem % 66, s = rem / 66;
        wTq[t3] = qkv_w[(s*64 + c)*66 + i];
    }
}

// ---------------- stem: masked 3x3 conv, 1->64, taps (0,0)(0,1)(0,2)(1,0) ----
__global__ __launch_bounds__(256) void k_stem(const float* __restrict__ x,
        const float* __restrict__ w, const float* __restrict__ bias,
        float* __restrict__ out, float* __restrict__ e_out)
{
    int b = blockIdx.x >> 5, h = blockIdx.x & 31;
    int t = threadIdx.x;
    int col = t & 31, slot = t >> 5;
    int hw = h*32 + col;
    const float* xb = x + b*NPix;
    float x00=0.f, x01=0.f, x02=0.f, x10=0.f;
    if (h > 0){
        if (col > 0)  x00 = xb[hw-33];
        x01 = xb[hw-32];
        if (col < 31) x02 = xb[hw-31];
    }
    if (col > 0) x10 = xb[hw-1];
    #pragma unroll
    for (int k2=0;k2<8;k2++){
        int o = slot*8 + k2;
        const float* wo = w + o*9;
        float v = bias[o] + wo[0]*x00 + wo[1]*x01 + wo[2]*x02 + wo[3]*x10;
        out[(b*64+o)*NPix + hw] = v;
        e_out[(b*64+o)*NPix + hw] = elu_f(v);
    }
}

// ---------------- bbA: 2x2 causal conv 64->64 on elu'd input, out = elu ----
// grid 1024 = (b*32+h)*4+og, 256 thr: slot = t>>5 (8), col = t&31; 2 out/thread.
// Activations staged in LDS (rows h-1, h); weights via 2 contiguous f4 loads.
__global__ __launch_bounds__(256) void k_bbA(const float* __restrict__ ein,
        const float* __restrict__ wT, const float* __restrict__ bias,
        float* __restrict__ t1e)
{
    __shared__ float eld[2*64*33];   // [r][i][cpos]; cpos = col+1, cpos0 = halo 0
    int blk = blockIdx.x;
    int og = blk & 3, h = (blk>>2) & 31, b = blk >> 7;
    int t = threadIdx.x;
    #pragma unroll
    for (int p = 0; p < 16; p++){
        int idx = t + p*256;         // 4096 = 128 ri x 32 col
        int ri = idx >> 5, col = idx & 31;
        int r = ri >> 6, i = ri & 63;
        int row = h - 1 + r;
        float v = (row >= 0) ? ein[(b*64+i)*NPix + row*32 + col] : 0.f;
        eld[ri*33 + 1 + col] = v;
    }
    if (t < 128) eld[t*33] = 0.f;
    __syncthreads();
    int col = t & 31, slot = t >> 5;
    int o0 = og*16 + slot*2;
    float acc0 = bias[o0], acc1 = bias[o0+1];
    const float4* wq = reinterpret_cast<const float4*>(wT);
    #pragma unroll 4
    for (int i=0;i<64;i++){
        float a00 = eld[i*33 + col];
        float a01 = eld[i*33 + col + 1];
        float a10 = eld[(64+i)*33 + col];
        float a11 = eld[(64+i)*33 + col + 1];
        float4 w0 = wq[i*64 + o0];
        float4 w1 = wq[i*64 + o0 + 1];
        acc0 = fmaf(w0.x, a00, acc0); acc0 = fmaf(w0.y, a01, acc0);
        acc0 = fmaf(w0.z, a10, acc0); acc0 = fmaf(w0.w, a11, acc0);
        acc1 = fmaf(w1.x, a00, acc1); acc1 = fmaf(w1.y, a01, acc1);
        acc1 = fmaf(w1.z, a10, acc1); acc1 = fmaf(w1.w, a11, acc1);
    }
    int gi = (b*64 + o0)*NPix + h*32 + col;
    t1e[gi]        = elu_f(acc0);
    t1e[gi + NPix] = elu_f(acc1);
}

// ---------------- bbB: 2x2 conv 64->128 + gate x + x1*sig(x2) ----
// grid 1024 = (b*32+h)*4+og, 256 thr; slot handles gate channels c0,c0+1
// (conv outputs c0,c0+1,c0+64,c0+65); paired weights: 4 contiguous f4/iter.
__global__ __launch_bounds__(256) void k_bbB(const float* __restrict__ ein,
        const float* __restrict__ xres, const float* __restrict__ wT,
        const float* __restrict__ bias,
        float* __restrict__ conv_out, float* __restrict__ e_out)
{
    __shared__ float eld[2*64*33];
    int blk = blockIdx.x;
    int og = blk & 3, h = (blk>>2) & 31, b = blk >> 7;
    int t = threadIdx.x;
    #pragma unroll
    for (int p = 0; p < 16; p++){
        int idx = t + p*256;
        int ri = idx >> 5, col = idx & 31;
        int r = ri >> 6, i = ri & 63;
        int row = h - 1 + r;
        float v = (row >= 0) ? ein[(b*64+i)*NPix + row*32 + col] : 0.f;
        eld[ri*33 + 1 + col] = v;
    }
    if (t < 128) eld[t*33] = 0.f;
    __syncthreads();
    int col = t & 31, slot = t >> 5;
    int c0 = og*16 + slot*2;
    float y0 = bias[c0], y1 = bias[c0+1];
    float z0 = bias[c0+64], z1 = bias[c0+65];
    const float4* wq = reinterpret_cast<const float4*>(wT);
    #pragma unroll 4
    for (int i=0;i<64;i++){
        float a00 = eld[i*33 + col];
        float a01 = eld[i*33 + col + 1];
        float a10 = eld[(64+i)*33 + col];
        float a11 = eld[(64+i)*33 + col + 1];
        const float4* wp = wq + i*128 + c0*2;   // [c0:y,z][c0+1:y,z]
        float4 wy0 = wp[0], wz0 = wp[1], wy1 = wp[2], wz1 = wp[3];
        y0 = fmaf(wy0.x, a00, y0); y0 = fmaf(wy0.y, a01, y0);
        y0 = fmaf(wy0.z, a10, y0); y0 = fmaf(wy0.w, a11, y0);
        z0 = fmaf(wz0.x, a00, z0); z0 = fmaf(wz0.y, a01, z0);
        z0 = fmaf(wz0.z, a10, z0); z0 = fmaf(wz0.w, a11, z0);
        y1 = fmaf(wy1.x, a00, y1); y1 = fmaf(wy1.y, a01, y1);
        y1 = fmaf(wy1.z, a10, y1); y1 = fmaf(wy1.w, a11, y1);
        z1 = fmaf(wz1.x, a00, z1); z1 = fmaf(wz1.y, a01, z1);
        z1 = fmaf(wz1.z, a10, z1); z1 = fmaf(wz1.w, a11, z1);
    }
    int gi = (b*64 + c0)*NPix + h*32 + col;
    float v0 = fmaf(y0, sig_f(z0), xres[gi]);
    float v1 = fmaf(y1, sig_f(z1), xres[gi + NPix]);
    conv_out[gi]        = v0;        conv_out[gi + NPix] = v1;
    e_out[gi]           = elu_f(v0); e_out[gi + NPix]    = elu_f(v1);
}

// ---------------- qkv 1x1: (conv 64ch + pos 2ch) -> q/k/v head layouts ----
__global__ __launch_bounds__(256) void k_qkv(const float* __restrict__ conv,
        const float* __restrict__ wt, const float* __restrict__ bias,
        float* __restrict__ qb, float* __restrict__ kb, float* __restrict__ vb)
{
    __shared__ float cl[66*64];
    int blk = blockIdx.x;
    int ohalf = blk & 1, tile = (blk>>1) & 15, b = blk >> 5;
    int hw0 = tile*64;
    int t = threadIdx.x;
    #pragma unroll
    for (int p=0;p<16;p++){
        int idx = t + p*256;
        int i = idx >> 6, px = idx & 63;
        cl[i*64 + px] = conv[(b*64+i)*NPix + hw0 + px];
    }
    if (t < 128){
        int px = t & 63;
        int hw = hw0 + px;
        float v = (t < 64) ? ((float)(hw>>5)*(1.f/32.f) - 0.5f)
                           : ((float)(hw&31)*(1.f/32.f) - 0.5f);
        cl[(64 + (t>>6))*64 + px] = v;
    }
    __syncthreads();
    int px = t & 63;
    int og = __builtin_amdgcn_readfirstlane(t >> 6);
    int c0 = ohalf*32 + og*8;
    int hw = hw0 + px;
    float acc[8];
    #pragma unroll
    for (int k=0;k<8;k++) acc[k] = bias[c0+k];
    #pragma unroll 2
    for (int i=0;i<66;i++){
        float e = cl[i*64 + px];
        #pragma unroll
        for (int k=0;k<8;k++)
            acc[k] = fmaf(wt[i*64 + c0 + k], e, acc[k]);
    }
    float4 f0 = {acc[0],acc[1],acc[2],acc[3]};
    float4 f1 = {acc[4],acc[5],acc[6],acc[7]};
    if (c0 < 32){
        float* dst = (c0 < 16) ? qb : kb;
        int cc = c0 & 15;
        reinterpret_cast<float4*>(dst)[(b*4 + (cc>>2))*NPix + hw] = f0;
        reinterpret_cast<float4*>(dst)[(b*4 + (cc>>2) + 1)*NPix + hw] = f1;
    } else {
        int c2 = c0 - 32;
        reinterpret_cast<float4*>(vb)[((b*4 + (c2>>3))*NPix + hw)*2]     = f0;
        reinterpret_cast<float4*>(vb)[((b*4 + (c2>>3))*NPix + hw)*2 + 1] = f1;
    }
}

// ---------------- causal attention: lane = query, uniform key index,
// per-lane softmax accum. grid 256 = bh*8 + p; 512 thr = 8 waves.
// Tiles ta=p, tb=15-p; wave w takes 1/8 of both tiles' key ranges (136 iters).
__global__ __launch_bounds__(512) void k_attn(const float* __restrict__ qb,
        const float* __restrict__ kb, const float* __restrict__ vb,
        float* __restrict__ ob)
{
    __shared__ float part[8][128][9];   // 36 KB
    int bh = blockIdx.x >> 3, p = blockIdx.x & 7;
    int ta = p, tb = 15 - p;
    int t = threadIdx.x;
    int lane = t & 63;
    int w = __builtin_amdgcn_readfirstlane(t >> 6);
    const float4* k4 = reinterpret_cast<const float4*>(kb) + bh*NPix;
    const float4* v4 = reinterpret_cast<const float4*>(vb) + bh*NPix*2;
    const float4* q4 = reinterpret_cast<const float4*>(qb) + bh*NPix;

    int qa = ta*64 + lane;
    float4 qva = q4[qa];
    float lsa = 0.f;
    float4 a0 = {0,0,0,0}, a1 = {0,0,0,0};
    int lenA = 8*(ta+1);
    int j0 = w*lenA, j1 = j0 + lenA;
    #pragma unroll 4
    for (int j = j0; j < j1; ++j){
        float4 kk = k4[j];
        float s = 0.5f*(qva.x*kk.x + qva.y*kk.y + qva.z*kk.z + qva.w*kk.w);
        float pe = (j <= qa) ? __expf(s) : 0.f;
        float4 v0 = v4[2*j], v1 = v4[2*j+1];
        lsa += pe;
        a0.x = fmaf(pe, v0.x, a0.x); a0.y = fmaf(pe, v0.y, a0.y);
        a0.z = fmaf(pe, v0.z, a0.z); a0.w = fmaf(pe, v0.w, a0.w);
        a1.x = fmaf(pe, v1.x, a1.x); a1.y = fmaf(pe, v1.y, a1.y);
        a1.z = fmaf(pe, v1.z, a1.z); a1.w = fmaf(pe, v1.w, a1.w);
    }
    int qbq = tb*64 + lane;
    float4 qvb = q4[qbq];
    float lsb = 0.f;
    float4 b0 = {0,0,0,0}, b1 = {0,0,0,0};
    int lenB = 8*(tb+1);
    int j2 = w*lenB, j3 = j2 + lenB;
    #pragma unroll 4
    for (int j = j2; j < j3; ++j){
        float4 kk = k4[j];
        float s = 0.5f*(qvb.x*kk.x + qvb.y*kk.y + qvb.z*kk.z + qvb.w*kk.w);
        float pe = (j <= qbq) ? __expf(s) : 0.f;
        float4 v0 = v4[2*j], v1 = v4[2*j+1];
        lsb += pe;
        b0.x = fmaf(pe, v0.x, b0.x); b0.y = fmaf(pe, v0.y, b0.y);
        b0.z = fmaf(pe, v0.z, b0.z); b0.w = fmaf(pe, v0.w, b0.w);
        b1.x = fmaf(pe, v1.x, b1.x); b1.y = fmaf(pe, v1.y, b1.y);
        b1.z = fmaf(pe, v1.z, b1.z); b1.w = fmaf(pe, v1.w, b1.w);
    }
    float* pa = part[w][lane];
    pa[0]=lsa; pa[1]=a0.x; pa[2]=a0.y; pa[3]=a0.z; pa[4]=a0.w;
    pa[5]=a1.x; pa[6]=a1.y; pa[7]=a1.z; pa[8]=a1.w;
    float* pbp = part[w][64+lane];
    pbp[0]=lsb; pbp[1]=b0.x; pbp[2]=b0.y; pbp[3]=b0.z; pbp[4]=b0.w;
    pbp[5]=b1.x; pbp[6]=b1.y; pbp[7]=b1.z; pbp[8]=b1.w;
    __syncthreads();
    if (t < 128){
        float s9[9];
        #pragma unroll
        for (int c=0;c<9;c++) s9[c] = part[0][t][c];
        #pragma unroll
        for (int ww=1;ww<8;ww++)
            #pragma unroll
            for (int c=0;c<9;c++) s9[c] += part[ww][t][c];
        float inv = 1.f / s9[0];
        int q = (t < 64) ? ta*64 + t : tb*64 + (t - 64);
        float4 r0 = {s9[1]*inv, s9[2]*inv, s9[3]*inv, s9[4]*inv};
        float4 r1 = {s9[5]*inv, s9[6]*inv, s9[7]*inv, s9[8]*inv};
        float4* od = reinterpret_cast<float4*>(ob);
        od[(bh*NPix + q)*2]     = r0;
        od[(bh*NPix + q)*2 + 1] = r1;
    }
}

// ---------------- epilogue: proj -> outa | outc | outp chain + residual ----
__global__ __launch_bounds__(256) void k_epi(const float* __restrict__ ob,
        const float* __restrict__ conv_raw, float* __restrict__ out,
        const float* __restrict__ pw,  const float* __restrict__ pb,
        const float* __restrict__ cw,  const float* __restrict__ cb2,
        const float* __restrict__ aw,  const float* __restrict__ ab,
        const float* __restrict__ ppw, const float* __restrict__ ppb,
        float* __restrict__ e_out)
{
    __shared__ float s_x[64][33];
    __shared__ float s_ov[32][33];
    __shared__ float s_e1[64][33];
    __shared__ float s_g[64][33];
    __shared__ float wl[14336];
    int b = blockIdx.x >> 5;
    int hw0 = (blockIdx.x & 31) * 32;
    int t = threadIdx.x;
    for (int idx = t; idx < 64*32; idx += 256){
        int i = idx >> 5, px = idx & 31;
        s_x[i][px] = elu_f(conv_raw[(b*64+i)*NPix + hw0 + px]);
    }
    for (int idx = t; idx < 32*32; idx += 256){
        int c = idx >> 5, px = idx & 31;
        s_ov[c][px] = ob[(b*4 + (c>>3))*NPix*8 + (hw0+px)*8 + (c&7)];
    }
    {
        float4* wl4 = reinterpret_cast<float4*>(wl);
        for (int idx = t; idx < 512; idx += 256)
            wl4[idx] = reinterpret_cast<const float4*>(pw)[idx];
        for (int idx = t; idx < 1024; idx += 256){
            wl4[512 + idx]  = reinterpret_cast<const float4*>(cw)[idx];
            wl4[1536 + idx] = reinterpret_cast<const float4*>(aw)[idx];
            wl4[2560 + idx] = reinterpret_cast<const float4*>(ppw)[idx];
        }
    }
    __syncthreads();
    int px = t & 31, g = t >> 5;
    int o0 = g*8;
    const float4* wp4  = reinterpret_cast<const float4*>(wl);
    const float4* wc4  = reinterpret_cast<const float4*>(wl + 2048);
    const float4* wa4  = reinterpret_cast<const float4*>(wl + 6144);
    const float4* wpp4 = reinterpret_cast<const float4*>(wl + 10240);
    float acc[8];
    #pragma unroll
    for (int k=0;k<8;k++) acc[k] = pb[o0+k];
    #pragma unroll
    for (int i4=0;i4<8;i4++){
        float v0 = s_ov[i4*4+0][px], v1 = s_ov[i4*4+1][px];
        float v2 = s_ov[i4*4+2][px], v3 = s_ov[i4*4+3][px];
        #pragma unroll
        for (int k=0;k<8;k++){
            float4 wv = wp4[(o0+k)*8 + i4];
            acc[k] = fmaf(wv.x, v0, acc[k]); acc[k] = fmaf(wv.y, v1, acc[k]);
            acc[k] = fmaf(wv.z, v2, acc[k]); acc[k] = fmaf(wv.w, v3, acc[k]);
        }
    }
    #pragma unroll
    for (int k=0;k<8;k++) s_e1[o0+k][px] = elu_f(acc[k]);
    __syncthreads();
    float aa[8], cc[8];
    #pragma unroll
    for (int k=0;k<8;k++){ aa[k] = ab[o0+k]; cc[k] = cb2[o0+k]; }
    #pragma unroll
    for (int i4=0;i4<16;i4++){
        float e0 = s_e1[i4*4+0][px], e1 = s_e1[i4*4+1][px];
        float e2 = s_e1[i4*4+2][px], e3 = s_e1[i4*4+3][px];
        float x0 = s_x[i4*4+0][px],  x1 = s_x[i4*4+1][px];
        float x2 = s_x[i4*4+2][px],  x3 = s_x[i4*4+3][px];
        #pragma unroll
        for (int k=0;k<8;k++){
            float4 wa = wa4[(o0+k)*16 + i4];
            float4 wc = wc4[(o0+k)*16 + i4];
            aa[k] = fmaf(wa.x, e0, aa[k]); aa[k] = fmaf(wa.y, e1, aa[k]);
            aa[k] = fmaf(wa.z, e2, aa[k]); aa[k] = fmaf(wa.w, e3, aa[k]);
            cc[k] = fmaf(wc.x, x0, cc[k]); cc[k] = fmaf(wc.y, x1, cc[k]);
            cc[k] = fmaf(wc.z, x2, cc[k]); cc[k] = fmaf(wc.w, x3, cc[k]);
        }
    }
    #pragma unroll
    for (int k=0;k<8;k++) s_g[o0+k][px] = elu_f(elu_f(aa[k]) + elu_f(cc[k]));
    __syncthreads();
    float bl[8];
    #pragma unroll
    for (int k=0;k<8;k++) bl[k] = ppb[o0+k];
    #pragma unroll
    for (int i4=0;i4<16;i4++){
        float g0 = s_g[i4*4+0][px], g1 = s_g[i4*4+1][px];
        float g2 = s_g[i4*4+2][px], g3 = s_g[i4*4+3][px];
        #pragma unroll
        for (int k=0;k<8;k++){
            float4 wv = wpp4[(o0+k)*16 + i4];
            bl[k] = fmaf(wv.x, g0, bl[k]); bl[k] = fmaf(wv.y, g1, bl[k]);
            bl[k] = fmaf(wv.z, g2, bl[k]); bl[k] = fmaf(wv.w, g3, bl[k]);
        }
    }
    #pragma unroll
    for (int k=0;k<8;k++){
        int gi = (b*64 + o0 + k)*NPix + hw0 + px;
        float on = elu_f(bl[k]) + out[gi];
        out[gi] = on;
        e_out[gi] = elu_f(on);
    }
}

// ---------------- final 1x1: logits = fc_w . elu(out) + fc_b ----
__global__ __launch_bounds__(256) void k_final(const float* __restrict__ out,
        const float* __restrict__ fw, const float* __restrict__ fb,
        float* __restrict__ logits)
{
    int idx = blockIdx.x*256 + threadIdx.x;      // 65536
    int pix = idx >> 3, sub = idx & 7;
    int b = pix >> 10, hw = pix & 1023;
    const float* obp = out + b*64*NPix + hw;
    float acc = 0.f;
    #pragma unroll
    for (int k=0;k<8;k++){
        int i = sub*8 + k;
        acc = fmaf(fw[i], elu_f(obp[i*NPix]), acc);
    }
    #pragma unroll
    for (int off=1; off<8; off<<=1) acc += __shfl_xor(acc, off);
    if (sub == 0) logits[pix] = acc + fb[0];
}

extern "C" void kernel_launch(void* const* d_in, const int* in_sizes, int n_in,
                              void* d_out, int out_size, void* d_ws, size_t ws_size,
                              hipStream_t stream)
{
    const float* x      = (const float*)d_in[0];
    const float* stem_w = (const float*)d_in[1];
    const float* stem_b = (const float*)d_in[2];
    const float* bb1_w  = (const float*)d_in[3];
    const float* bb1_b  = (const float*)d_in[4];
    const float* bb2_w  = (const float*)d_in[5];
    const float* bb2_b  = (const float*)d_in[6];
    const float* qkv_w  = (const float*)d_in[7];
    const float* qkv_b  = (const float*)d_in[8];
    const float* proj_w = (const float*)d_in[9];
    const float* proj_b = (const float*)d_in[10];
    const float* outc_w = (const float*)d_in[11];
    const float* outc_b = (const float*)d_in[12];
    const float* outa_w = (const float*)d_in[13];
    const float* outa_b = (const float*)d_in[14];
    const float* outp_w = (const float*)d_in[15];
    const float* outp_b = (const float*)d_in[16];
    const float* fc_w   = (const float*)d_in[17];
    const float* fc_b   = (const float*)d_in[18];
    float* logits = (float*)d_out;

    float* W        = (float*)d_ws;
    float* out_buf  = W;                  // B*64*N = 524288
    float* e_conv   = W + 524288;
    float* conv_raw = W + 2*524288;
    float* t1e      = W + 3*524288;
    float* qbuf     = W + 4*524288;       // [b][h][n][4]
    float* kbuf     = qbuf + 131072;
    float* vbuf     = kbuf + 131072;      // [b][h][n][8]
    float* obuf     = vbuf + 262144;      // [b][h][n][8]
    float* wT1      = obuf + 262144;      // 16*64*64*4 = 262144
    float* wT2      = wT1 + 262144;       // 16*64*64*2*4 = 524288
    float* wTq      = wT2 + 524288;       // 8*66*64 = 33792

    k_wT<<<900,256,0,stream>>>(bb1_w, bb2_w, qkv_w, wT1, wT2, wTq);
    k_stem<<<256,256,0,stream>>>(x, stem_w, stem_b, out_buf, e_conv);
    for (int s=0;s<8;s++){
        for (int l=0;l<2;l++){
            int sl = s*2+l;
            k_bbA<<<1024,256,0,stream>>>(e_conv, wT1 + sl*16384, bb1_b + sl*64, t1e);
            const float* xres = (l==0) ? out_buf : conv_raw;
            k_bbB<<<1024,256,0,stream>>>(t1e, xres, wT2 + sl*32768, bb2_b + sl*128,
                                         conv_raw, e_conv);
        }
        k_qkv<<<256,256,0,stream>>>(conv_raw, wTq + s*4224, qkv_b + s*64,
                                    qbuf, kbuf, vbuf);
        k_attn<<<256,512,0,stream>>>(qbuf, kbuf, vbuf, obuf);
        k_epi<<<256,256,0,stream>>>(obuf, conv_raw, out_buf,
                                    proj_w + s*2048, proj_b + s*64,
                                    outc_w + s*4096, outc_b + s*64,
                                    outa_w + s*4096, outa_b + s*64,
                                    outp_w + s*4096, outp_b + s*64,
                                    e_conv);
    }
    k_final<<<256,256,0,stream>>>(out_buf, fc_w, fc_b, logits);
}